// Round 2
// 89.535 us; speedup vs baseline: 1.0140x; 1.0140x over previous
//
#include <hip/hip_runtime.h>

// Problem constants (reference shapes)
#define BQ 16
#define NP 4096
#define MP 4096

constexpr int TPB = 256;                        // 4 waves (R5 lesson: NOT 512)
constexpr int WAVES = 4;
constexpr int FR = 2;                           // B-fragments (32 cols) per wave
constexpr int SRC_PER_BLOCK = 32 * FR * WAVES;  // 256 columns per block
constexpr int CHUNK = 256;                      // rows per LDS chunk (8 KB expanded)
constexpr int NCH = MP / CHUNK;                 // 16 chunks

typedef __bf16 bf16x8 __attribute__((ext_vector_type(8)));
typedef float f32x16 __attribute__((ext_vector_type(16)));

union Frag {
    unsigned short u[8];
    bf16x8 v;
    int4 i4;
};

// RNE float -> bf16 bits (no NaN inputs here)
__device__ inline unsigned short f2bf(float f) {
    unsigned u = __float_as_uint(f);
    return (unsigned short)((u + 0x7FFFu + ((u >> 16) & 1u)) >> 16);
}
__device__ inline float bf2f(unsigned short h) {
    return __uint_as_float(((unsigned)h) << 16);
}

__global__ void chamfer_zero_kernel(float* __restrict__ out) { out[0] = 0.0f; }

// Expand one row point (cx,cy,cz) into its two 16B K-planes of the A operand.
// K-layout (bit-exact hi/lo split, verified R3):
//   k0..2 : x,y,z hi      (dot with -2s hi)
//   k3..5 : x,y,z hi      (dot with -2s lo)
//   k6..8 : x,y,z lo      (dot with -2s hi)
//   k9..10: t2 hi/lo      (dot with 1)
//   k11..12: 1,1          (dot with s2 hi/lo)
__device__ inline void stage_row(float cx, float cy, float cz,
                                 unsigned short* __restrict__ shbuf,
                                 int sub, int row) {
    const unsigned short ONE = 0x3F80;  // bf16(1.0)
    unsigned short xh = f2bf(cx), yh = f2bf(cy), zh = f2bf(cz);
    unsigned short xl = f2bf(cx - bf2f(xh));
    unsigned short yl = f2bf(cy - bf2f(yh));
    unsigned short zl = f2bf(cz - bf2f(zh));
    float t2 = fmaf(cx, cx, fmaf(cy, cy, cz * cz));
    unsigned short t2h = f2bf(t2), t2l = f2bf(t2 - bf2f(t2h));
    Frag p0, p1;
    p0.u[0] = xh; p0.u[1] = yh; p0.u[2] = zh;   // k0..2: hi  (x -2s hi)
    p0.u[3] = xh; p0.u[4] = yh; p0.u[5] = zh;   // k3..5: hi  (x -2s lo)
    p0.u[6] = xl; p0.u[7] = yl;                 // k6..7: lo x,y (x -2s hi)
    p1.u[0] = zl;                               // k8:    lo z
    p1.u[1] = t2h; p1.u[2] = t2l;               // k9..10: t2 (x 1)
    p1.u[3] = ONE; p1.u[4] = ONE;               // k11..12: 1 (x s2 hi/lo)
    p1.u[5] = 0; p1.u[6] = 0; p1.u[7] = 0;
    *(int4*)&shbuf[((sub * 2 + 0) * 32 + row) * 8] = p0.i4;
    *(int4*)&shbuf[((sub * 2 + 1) * 32 + row) * 8] = p1.i4;
}

// ---------------------------------------------------------------------------
// Single fused MFMA chamfer kernel. grid = (NP/SRC_PER_BLOCK, 2*BQ) = (16, 32)
// = 512 blocks (2/CU, 8 waves/CU).
// d2(i,j) = K=13 bf16 dot (hi/lo split, bit-exact-verified R3): rows (A)
// stream through a DOUBLE-BUFFERED 2x8 KB LDS chunk; each wave holds FR=2
// fixed B-fragments (64 source columns), so each A-frag ds_read_b128 feeds
// 2 MFMAs. R6 change: stage chunk c+1 into sh[p^1] while computing sh[p]
// -> ONE barrier per chunk (16) instead of two (32); barrier drain was the
// largest remaining non-floor term (min-tree VALU floor ~3.4 us).
// 16 C-regs per MFMA = 16 rows of one column -> in-lane min3 tree, xor-32
// fold, clamp, block sum, one weighted atomicAdd.
// No d_ws use (ws re-poison fill costs ~43 us in the timed stream).
// ---------------------------------------------------------------------------
__global__ __launch_bounds__(TPB) void chamfer_mfma_kernel(
    const float* __restrict__ srcp,   // [BQ][NP][3]
    const float* __restrict__ tgtp,   // [BQ][MP][3]
    const float* __restrict__ wts,    // [BQ]
    float* __restrict__ out)          // scalar
{
    const int gy  = blockIdx.y;
    const int dir = gy >> 4;
    const int b   = gy & 15;
    // dir0: cols(B)=src points, rows(A)=tgt points; dir1: swapped.
    const float* S = dir ? (tgtp + (size_t)b * MP * 3) : (srcp + (size_t)b * NP * 3);
    const float* T = dir ? (srcp + (size_t)b * NP * 3) : (tgtp + (size_t)b * MP * 3);

    const int tid  = threadIdx.x;
    const int lane = tid & 63;
    const int half = lane >> 5;   // K-half selector for A/B operands
    const int col  = lane & 31;
    const int wave = tid >> 6;

    // [2 buf][8 sub][2 half][32 row][8 short] = 16 KB; A-read lane-stride 16 B
    // within a (sub,half) plane -> conflict-free (R3 measured
    // SQ_LDS_BANK_CONFLICT=0; buf1 at +8 KB preserves the bank pattern).
    __shared__ unsigned short sh[2][CHUNK * 16];
    __shared__ float partial[WAVES];

    const unsigned short ONE = 0x3F80;  // bf16(1.0)

    // ---- FR fixed B-fragments (source side) ----
    Frag bfr[FR];
#pragma unroll
    for (int f = 0; f < FR; ++f) {
        const int sidx = blockIdx.x * SRC_PER_BLOCK + (wave * FR + f) * 32 + col;
        const float* sp = S + (size_t)sidx * 3;
        float x = sp[0], y = sp[1], z = sp[2];
        unsigned short uh0 = f2bf(-2.0f * x), uh1 = f2bf(-2.0f * y), uh2 = f2bf(-2.0f * z);
        unsigned short ul0 = f2bf(-2.0f * x - bf2f(uh0));
        unsigned short ul1 = f2bf(-2.0f * y - bf2f(uh1));
        unsigned short ul2 = f2bf(-2.0f * z - bf2f(uh2));
        float s2 = fmaf(x, x, fmaf(y, y, z * z));
        unsigned short s2h = f2bf(s2), s2l = f2bf(s2 - bf2f(s2h));
        if (half == 0) {  // k = 0..7
            bfr[f].u[0] = uh0; bfr[f].u[1] = uh1; bfr[f].u[2] = uh2;
            bfr[f].u[3] = ul0; bfr[f].u[4] = ul1; bfr[f].u[5] = ul2;
            bfr[f].u[6] = uh0; bfr[f].u[7] = uh1;
        } else {          // k = 8..15
            bfr[f].u[0] = uh2; bfr[f].u[1] = ONE; bfr[f].u[2] = ONE;
            bfr[f].u[3] = s2h; bfr[f].u[4] = s2l;
            bfr[f].u[5] = 0;   bfr[f].u[6] = 0;  bfr[f].u[7] = 0;
        }
    }

    float accm[FR];
#pragma unroll
    for (int f = 0; f < FR; ++f) accm[f] = __int_as_float(0x7F800000);

    const f32x16 zc = {};
    const int sub = tid >> 5, row = tid & 31;

    // ---- prologue: stage chunk 0 into buf0, issue chunk 1's point load ----
    float cx, cy, cz;
    {
        const float* tp = T + (size_t)tid * 3;
        cx = tp[0]; cy = tp[1]; cz = tp[2];
    }
    stage_row(cx, cy, cz, sh[0], sub, row);
    {
        const float* tp = T + (size_t)(CHUNK + tid) * 3;
        cx = tp[0]; cy = tp[1]; cz = tp[2];
    }
    __syncthreads();

    for (int c = 0; c < NCH; ++c) {  // 16 chunks of 256 rows
        const int p = c & 1;

        // ---- stage NEXT chunk into the other buffer (no barrier needed:
        // writers touch sh[p^1], readers below touch sh[p]; the barrier at
        // the end of the previous iteration guaranteed sh[p^1]'s readers are
        // done). Then issue chunk c+2's point load (hidden under compute).
        if (c + 1 < NCH) {
            stage_row(cx, cy, cz, sh[p ^ 1], sub, row);
            if (c + 2 < NCH) {
                const float* tp = T + (size_t)((c + 2) * CHUNK + tid) * 3;
                cx = tp[0]; cy = tp[1]; cz = tp[2];
            }
        }

        // ---- 8 sub-chunks; each A-fragment feeds FR=2 MFMAs ----
#pragma unroll
        for (int sc = 0; sc < CHUNK / 32; ++sc) {
            Frag a;
            a.i4 = *(const int4*)&sh[p][((sc * 2 + half) * 32 + col) * 8];
#pragma unroll
            for (int f = 0; f < FR; ++f) {
                f32x16 d = __builtin_amdgcn_mfma_f32_32x32x16_bf16(a.v, bfr[f].v, zc, 0, 0, 0);
                float m0 = fminf(fminf(d[0], d[1]), d[2]);
                float m1 = fminf(fminf(d[3], d[4]), d[5]);
                float m2 = fminf(fminf(d[6], d[7]), d[8]);
                float m3 = fminf(fminf(d[9], d[10]), d[11]);
                float m4 = fminf(fminf(d[12], d[13]), d[14]);
                float t0 = fminf(fminf(m0, m1), m2);
                float t1 = fminf(fminf(m3, m4), d[15]);
                accm[f] = fminf(fminf(accm[f], t0), t1);
            }
        }

        // One barrier per chunk: ensures (a) sh[p^1] staging complete before
        // next iteration reads it, (b) sh[p] reads complete before the
        // iteration after next overwrites it. Skip after the last chunk.
        if (c + 1 < NCH) __syncthreads();
    }

    // ---- epilogue: fold row-halves, clamp, sum this wave's 64 columns ----
    float tot = 0.0f;
#pragma unroll
    for (int f = 0; f < FR; ++f) {
        float m = fminf(accm[f], __shfl_xor(accm[f], 32, 64));
        tot += fmaxf(m, 0.0f);
    }
#pragma unroll
    for (int off = 32; off > 0; off >>= 1) tot += __shfl_xor(tot, off, 64);
    if (lane == 0) partial[wave] = tot * 0.5f;  // each column counted twice
    __syncthreads();
    if (tid == 0) {
        float v = partial[0] + partial[1] + partial[2] + partial[3];
        atomicAdd(out, v * wts[b] * (1.0f / ((float)NP * (float)BQ)));
    }
}

// ---------------------------------------------------------------------------
extern "C" void kernel_launch(void* const* d_in, const int* in_sizes, int n_in,
                              void* d_out, int out_size, void* d_ws, size_t ws_size,
                              hipStream_t stream) {
    const float* src = (const float*)d_in[0];
    const float* tgt = (const float*)d_in[1];
    const float* wts = (const float*)d_in[2];
    float* out = (float*)d_out;

    chamfer_zero_kernel<<<1, 1, 0, stream>>>(out);

    dim3 grid(NP / SRC_PER_BLOCK, 2 * BQ);  // (16, 32) = 512 blocks
    chamfer_mfma_kernel<<<grid, TPB, 0, stream>>>(src, tgt, wts, out);
}

// Round 4
// 89.322 us; speedup vs baseline: 1.0164x; 1.0024x over previous
//
#include <hip/hip_runtime.h>

// Problem constants (reference shapes)
#define BQ 16
#define NP 4096
#define MP 4096

constexpr int TPB = 256;                        // 4 waves (R5 lesson: NOT 512)
constexpr int WAVES = 4;
constexpr int FR = 2;                           // B-fragments (32 cols) per wave
constexpr int SRC_PER_BLOCK = 32 * FR * WAVES;  // 256 columns per block
constexpr int CHUNK = 256;                      // rows per LDS chunk (8 KB expanded)
constexpr int NCH = MP / CHUNK;                 // 16 chunks

typedef __bf16 bf16x8 __attribute__((ext_vector_type(8)));
typedef float f32x16 __attribute__((ext_vector_type(16)));

union Frag {
    unsigned short u[8];
    bf16x8 v;
    int4 i4;
};

// RNE float -> bf16 bits (no NaN inputs here)
__device__ inline unsigned short f2bf(float f) {
    unsigned u = __float_as_uint(f);
    return (unsigned short)((u + 0x7FFFu + ((u >> 16) & 1u)) >> 16);
}
__device__ inline float bf2f(unsigned short h) {
    return __uint_as_float(((unsigned)h) << 16);
}

__global__ void chamfer_zero_kernel(float* __restrict__ out) { out[0] = 0.0f; }

// Expand one row point (cx,cy,cz) into its two 16B K-planes of the A operand.
// K-layout (bit-exact hi/lo split, verified R3):
//   k0..2 : x,y,z hi      (dot with -2s hi)
//   k3..5 : x,y,z hi      (dot with -2s lo)
//   k6..8 : x,y,z lo      (dot with -2s hi)
//   k9..10: t2 hi/lo      (dot with 1)
//   k11..12: 1,1          (dot with s2 hi/lo)
__device__ inline void stage_row(float cx, float cy, float cz,
                                 unsigned short* __restrict__ shbuf,
                                 int sub, int row) {
    const unsigned short ONE = 0x3F80;  // bf16(1.0)
    unsigned short xh = f2bf(cx), yh = f2bf(cy), zh = f2bf(cz);
    unsigned short xl = f2bf(cx - bf2f(xh));
    unsigned short yl = f2bf(cy - bf2f(yh));
    unsigned short zl = f2bf(cz - bf2f(zh));
    float t2 = fmaf(cx, cx, fmaf(cy, cy, cz * cz));
    unsigned short t2h = f2bf(t2), t2l = f2bf(t2 - bf2f(t2h));
    Frag p0, p1;
    p0.u[0] = xh; p0.u[1] = yh; p0.u[2] = zh;   // k0..2: hi  (x -2s hi)
    p0.u[3] = xh; p0.u[4] = yh; p0.u[5] = zh;   // k3..5: hi  (x -2s lo)
    p0.u[6] = xl; p0.u[7] = yl;                 // k6..7: lo x,y (x -2s hi)
    p1.u[0] = zl;                               // k8:    lo z
    p1.u[1] = t2h; p1.u[2] = t2l;               // k9..10: t2 (x 1)
    p1.u[3] = ONE; p1.u[4] = ONE;               // k11..12: 1 (x s2 hi/lo)
    p1.u[5] = 0; p1.u[6] = 0; p1.u[7] = 0;
    *(int4*)&shbuf[((sub * 2 + 0) * 32 + row) * 8] = p0.i4;
    *(int4*)&shbuf[((sub * 2 + 1) * 32 + row) * 8] = p1.i4;
}

// ---------------------------------------------------------------------------
// Single fused MFMA chamfer kernel. grid = (NP/SRC_PER_BLOCK, 2*BQ) = (16, 32)
// = 512 blocks (2/CU, 8 waves/CU).
// d2(i,j) = K=13 bf16 dot (hi/lo split, bit-exact-verified R3): rows (A)
// stream through a DOUBLE-BUFFERED 2x8 KB LDS chunk; each wave holds FR=2
// fixed B-fragments (64 source columns), so each A-frag ds_read_b128 feeds
// 2 MFMAs. R6: one barrier per chunk via dbuf (33->16; verified bit-exact,
// 89.53 us). R7 (CHUNK=512) FAILED correctness nondeterministically and is
// REVERTED -- do not re-attempt chunk doubling without a race mechanism.
// 16 C-regs per MFMA = 16 rows of one column -> in-lane min3 tree, xor-32
// fold, clamp, block sum, one weighted atomicAdd.
// No d_ws use (ws re-poison fill costs ~43 us in the timed stream).
// ---------------------------------------------------------------------------
__global__ __launch_bounds__(TPB) void chamfer_mfma_kernel(
    const float* __restrict__ srcp,   // [BQ][NP][3]
    const float* __restrict__ tgtp,   // [BQ][MP][3]
    const float* __restrict__ wts,    // [BQ]
    float* __restrict__ out)          // scalar
{
    const int gy  = blockIdx.y;
    const int dir = gy >> 4;
    const int b   = gy & 15;
    // dir0: cols(B)=src points, rows(A)=tgt points; dir1: swapped.
    const float* S = dir ? (tgtp + (size_t)b * MP * 3) : (srcp + (size_t)b * NP * 3);
    const float* T = dir ? (srcp + (size_t)b * NP * 3) : (tgtp + (size_t)b * MP * 3);

    const int tid  = threadIdx.x;
    const int lane = tid & 63;
    const int half = lane >> 5;   // K-half selector for A/B operands
    const int col  = lane & 31;
    const int wave = tid >> 6;

    // [2 buf][8 sub][2 half][32 row][8 short] = 16 KB; A-read lane-stride 16 B
    // within a (sub,half) plane -> conflict-free (R3 measured
    // SQ_LDS_BANK_CONFLICT=0; buf1 at +8 KB preserves the bank pattern).
    __shared__ unsigned short sh[2][CHUNK * 16];
    __shared__ float partial[WAVES];

    const unsigned short ONE = 0x3F80;  // bf16(1.0)

    // ---- FR fixed B-fragments (source side) ----
    Frag bfr[FR];
#pragma unroll
    for (int f = 0; f < FR; ++f) {
        const int sidx = blockIdx.x * SRC_PER_BLOCK + (wave * FR + f) * 32 + col;
        const float* sp = S + (size_t)sidx * 3;
        float x = sp[0], y = sp[1], z = sp[2];
        unsigned short uh0 = f2bf(-2.0f * x), uh1 = f2bf(-2.0f * y), uh2 = f2bf(-2.0f * z);
        unsigned short ul0 = f2bf(-2.0f * x - bf2f(uh0));
        unsigned short ul1 = f2bf(-2.0f * y - bf2f(uh1));
        unsigned short ul2 = f2bf(-2.0f * z - bf2f(uh2));
        float s2 = fmaf(x, x, fmaf(y, y, z * z));
        unsigned short s2h = f2bf(s2), s2l = f2bf(s2 - bf2f(s2h));
        if (half == 0) {  // k = 0..7
            bfr[f].u[0] = uh0; bfr[f].u[1] = uh1; bfr[f].u[2] = uh2;
            bfr[f].u[3] = ul0; bfr[f].u[4] = ul1; bfr[f].u[5] = ul2;
            bfr[f].u[6] = uh0; bfr[f].u[7] = uh1;
        } else {          // k = 8..15
            bfr[f].u[0] = uh2; bfr[f].u[1] = ONE; bfr[f].u[2] = ONE;
            bfr[f].u[3] = s2h; bfr[f].u[4] = s2l;
            bfr[f].u[5] = 0;   bfr[f].u[6] = 0;  bfr[f].u[7] = 0;
        }
    }

    float accm[FR];
#pragma unroll
    for (int f = 0; f < FR; ++f) accm[f] = __int_as_float(0x7F800000);

    const f32x16 zc = {};
    const int sub = tid >> 5, row = tid & 31;

    // ---- prologue: stage chunk 0 into buf0, issue chunk 1's point load ----
    float cx, cy, cz;
    {
        const float* tp = T + (size_t)tid * 3;
        cx = tp[0]; cy = tp[1]; cz = tp[2];
    }
    stage_row(cx, cy, cz, sh[0], sub, row);
    {
        const float* tp = T + (size_t)(CHUNK + tid) * 3;
        cx = tp[0]; cy = tp[1]; cz = tp[2];
    }
    __syncthreads();

    for (int c = 0; c < NCH; ++c) {  // 16 chunks of 256 rows
        const int p = c & 1;

        // ---- stage NEXT chunk into the other buffer (no barrier needed:
        // writers touch sh[p^1], readers below touch sh[p]; the barrier at
        // the end of the previous iteration guaranteed sh[p^1]'s readers are
        // done). Then issue chunk c+2's point load (hidden under compute).
        if (c + 1 < NCH) {
            stage_row(cx, cy, cz, sh[p ^ 1], sub, row);
            if (c + 2 < NCH) {
                const float* tp = T + (size_t)((c + 2) * CHUNK + tid) * 3;
                cx = tp[0]; cy = tp[1]; cz = tp[2];
            }
        }

        // ---- 8 sub-chunks; each A-fragment feeds FR=2 MFMAs ----
#pragma unroll
        for (int sc = 0; sc < CHUNK / 32; ++sc) {
            Frag a;
            a.i4 = *(const int4*)&sh[p][((sc * 2 + half) * 32 + col) * 8];
#pragma unroll
            for (int f = 0; f < FR; ++f) {
                f32x16 d = __builtin_amdgcn_mfma_f32_32x32x16_bf16(a.v, bfr[f].v, zc, 0, 0, 0);
                float m0 = fminf(fminf(d[0], d[1]), d[2]);
                float m1 = fminf(fminf(d[3], d[4]), d[5]);
                float m2 = fminf(fminf(d[6], d[7]), d[8]);
                float m3 = fminf(fminf(d[9], d[10]), d[11]);
                float m4 = fminf(fminf(d[12], d[13]), d[14]);
                float t0 = fminf(fminf(m0, m1), m2);
                float t1 = fminf(fminf(m3, m4), d[15]);
                accm[f] = fminf(fminf(accm[f], t0), t1);
            }
        }

        // One barrier per chunk: ensures (a) sh[p^1] staging complete before
        // next iteration reads it, (b) sh[p] reads complete before the
        // iteration after next overwrites it. Skip after the last chunk.
        if (c + 1 < NCH) __syncthreads();
    }

    // ---- epilogue: fold row-halves, clamp, sum this wave's 64 columns ----
    float tot = 0.0f;
#pragma unroll
    for (int f = 0; f < FR; ++f) {
        float m = fminf(accm[f], __shfl_xor(accm[f], 32, 64));
        tot += fmaxf(m, 0.0f);
    }
#pragma unroll
    for (int off = 32; off > 0; off >>= 1) tot += __shfl_xor(tot, off, 64);
    if (lane == 0) partial[wave] = tot * 0.5f;  // each column counted twice
    __syncthreads();
    if (tid == 0) {
        float v = partial[0] + partial[1] + partial[2] + partial[3];
        atomicAdd(out, v * wts[b] * (1.0f / ((float)NP * (float)BQ)));
    }
}

// ---------------------------------------------------------------------------
extern "C" void kernel_launch(void* const* d_in, const int* in_sizes, int n_in,
                              void* d_out, int out_size, void* d_ws, size_t ws_size,
                              hipStream_t stream) {
    const float* src = (const float*)d_in[0];
    const float* tgt = (const float*)d_in[1];
    const float* wts = (const float*)d_in[2];
    float* out = (float*)d_out;

    chamfer_zero_kernel<<<1, 1, 0, stream>>>(out);

    dim3 grid(NP / SRC_PER_BLOCK, 2 * BQ);  // (16, 32) = 512 blocks
    chamfer_mfma_kernel<<<grid, TPB, 0, stream>>>(src, tgt, wts, out);
}